// Round 12
// baseline (979.298 us; speedup 1.0000x reference)
//
#include <hip/hip_runtime.h>
#include <hip/hip_bf16.h>

#define NODES_C 64
#define HEADS 4
#define HEAD_D 16

// f32 -> bf16 with round-to-nearest-even (deterministic, branch-free)
__device__ __forceinline__ unsigned short f32_to_bf16(float f) {
    unsigned int x = __float_as_uint(f);
    unsigned int r = x + 0x7fffu + ((x >> 16) & 1u);
    return (unsigned short)(r >> 16);
}

// ---------------------------------------------------------------------------
// CSR build
// ---------------------------------------------------------------------------
__global__ void count_k(const int* __restrict__ dst, int E, int* __restrict__ deg) {
    int e = blockIdx.x * blockDim.x + threadIdx.x;
    if (e < E) atomicAdd(&deg[dst[e]], 1);
}

__global__ __launch_bounds__(1024) void scan_chunk(const int* __restrict__ deg,
                                                   int* __restrict__ excl,
                                                   int* __restrict__ chunkSums, int N) {
    __shared__ int buf[1024];
    int i = blockIdx.x * 1024 + threadIdx.x;
    int v = (i < N) ? deg[i] : 0;
    buf[threadIdx.x] = v;
    __syncthreads();
    for (int off = 1; off < 1024; off <<= 1) {
        int t = (threadIdx.x >= off) ? buf[threadIdx.x - off] : 0;
        __syncthreads();
        buf[threadIdx.x] += t;
        __syncthreads();
    }
    if (i < N) excl[i] = buf[threadIdx.x] - v;   // exclusive within chunk
    if (threadIdx.x == 1023) chunkSums[blockIdx.x] = buf[1023];
}

__global__ __launch_bounds__(128) void scan_sums(int* __restrict__ chunkSums, int nChunks) {
    __shared__ int buf[128];
    int v = (threadIdx.x < nChunks) ? chunkSums[threadIdx.x] : 0;
    buf[threadIdx.x] = v;
    __syncthreads();
    for (int off = 1; off < 128; off <<= 1) {
        int t = (threadIdx.x >= off) ? buf[threadIdx.x - off] : 0;
        __syncthreads();
        buf[threadIdx.x] += t;
        __syncthreads();
    }
    if (threadIdx.x < nChunks) chunkSums[threadIdx.x] = buf[threadIdx.x] - v;  // exclusive
}

__global__ void scan_add(int* __restrict__ excl, const int* __restrict__ chunkSums,
                         int N, int E) {
    int i = blockIdx.x * blockDim.x + threadIdx.x;
    if (i < N) excl[i] += chunkSums[i >> 10];
    if (i == 0) excl[N] = E;
}

__global__ void fill_k(const int* __restrict__ dst, int E,
                       const int* __restrict__ row_start, int* __restrict__ cursor,
                       int* __restrict__ csr) {
    int e = blockIdx.x * blockDim.x + threadIdx.x;
    if (e < E) {
        int d = dst[e];
        int pos = atomicAdd(&cursor[d], 1);
        csr[row_start[d] + pos] = e;
    }
}

// ---------------------------------------------------------------------------
// DETERMINISM (verified R9): sort each CSR row by edge id so the atomic
// fill order doesn't leak into f32 summation order. One thread per row.
// ---------------------------------------------------------------------------
__global__ void sort_rows_k(const int* __restrict__ row_start, int* __restrict__ csr,
                            int N) {
    int i = blockIdx.x * blockDim.x + threadIdx.x;
    if (i >= N) return;
    int beg = row_start[i], end = row_start[i + 1];
    for (int p = beg + 1; p < end; ++p) {
        int key = csr[p];
        int j = p - 1;
        while (j >= beg && csr[j] > key) { csr[j + 1] = csr[j]; --j; }
        csr[j + 1] = key;
    }
}

// ---------------------------------------------------------------------------
// One-time edge-data permutation into CSR order.
// ---------------------------------------------------------------------------
__global__ void gather_edges(const int* __restrict__ csr, const int* __restrict__ srcA,
                             const float4* __restrict__ ea4,
                             int* __restrict__ csr_src, float4* __restrict__ csr_ea,
                             int E) {
    int t = blockIdx.x * blockDim.x + threadIdx.x;
    int p = t >> 2, q = t & 3;
    if (p < E) {
        int e = csr[p];
        if (q == 0) csr_src[p] = srcA[e];
        csr_ea[(size_t)p * 4 + q] = ea4[(size_t)e * 4 + q];
    }
}

// ---------------------------------------------------------------------------
// Fused node projections. K/V stored as BF16 PAIRS: one 4B word per channel
// holds {K (lo 16), V (hi 16)}. Q / Ssk stay f32. (verified R11)
// ---------------------------------------------------------------------------
#define GB 16
__global__ __launch_bounds__(256) void gemm_qkvs(
    const float* __restrict__ Hin,
    const float* __restrict__ Wq, const float* __restrict__ bq,
    const float* __restrict__ Wk, const float* __restrict__ bk,
    const float* __restrict__ Wv, const float* __restrict__ bv,
    const float* __restrict__ Ws, const float* __restrict__ bs,
    float* __restrict__ Q, unsigned short* __restrict__ KVh,
    float* __restrict__ Ssk, int N)
{
    int m = threadIdx.x >> 6;
    int c = threadIdx.x & 63;
    const float* W = (m == 0) ? Wq : (m == 1) ? Wk : (m == 2) ? Wv : Ws;
    const float* b = (m == 0) ? bq : (m == 1) ? bk : (m == 2) ? bv : bs;
    int cOff = (m == 1) ? 2 * c : (m == 2) ? 2 * c + 1 : c;

    float wcol[64];
#pragma unroll
    for (int t = 0; t < 64; ++t) wcol[t] = W[t * 64 + c];
    float bias = b[c];

    __shared__ __align__(16) float hrow[GB][64];

    for (int base = blockIdx.x * GB; base < N; base += gridDim.x * GB) {
        int nn = min(GB, N - base);
        __syncthreads();
        for (int idx = threadIdx.x; idx < nn * 64; idx += 256)
            hrow[idx >> 6][idx & 63] = Hin[base * 64 + idx];
        __syncthreads();
        for (int r = 0; r < nn; ++r) {
            const float4* h4 = (const float4*)hrow[r];
            float acc = bias;
#pragma unroll
            for (int t4 = 0; t4 < 16; ++t4) {
                float4 hv = h4[t4];
                acc += hv.x * wcol[4 * t4 + 0];
                acc += hv.y * wcol[4 * t4 + 1];
                acc += hv.z * wcol[4 * t4 + 2];
                acc += hv.w * wcol[4 * t4 + 3];
            }
            // m is wave-uniform -> no divergence
            if (m == 0)      Q  [(size_t)(base + r) * 64 + c] = acc;
            else if (m == 3) Ssk[(size_t)(base + r) * 64 + c] = acc;
            else             KVh[(size_t)(base + r) * 128 + cOff] = f32_to_bf16(acc);
        }
    }
}

// ---------------------------------------------------------------------------
// Edge-softmax attention, bf16 KV (R11) + SOFTWARE-PIPELINED index/ea
// prefetch: iteration n issues KV gathers for already-loaded indices, then
// issues iteration n+1's index+ea loads, THEN computes (waiting only on the
// KV gathers; next-iter loads stay in flight). Breaks the 2-round dependent
// chain  idx -> KV -> compute  that R10/R11 counters showed was the stall.
// ---------------------------------------------------------------------------
#define KV_DECODE(u, kf, vf)                                \
    kf = __uint_as_float((u) << 16);                        \
    vf = __uint_as_float((u) & 0xffff0000u);

__global__ __launch_bounds__(256) void attn_pre(
    const float* __restrict__ Q, const unsigned int* __restrict__ KVu,
    const float* __restrict__ Ssk,
    const int* __restrict__ row_start, const int* __restrict__ csr_src,
    const float* __restrict__ csr_ea,      // [E][16], CSR order
    const float* __restrict__ We, const float* __restrict__ be,
    float* __restrict__ Hout, int N, int doRelu)
{
    __shared__ float weS[16 * 68];          // padded rows
    for (int idx = threadIdx.x; idx < 1024; idx += 256)
        weS[(idx >> 6) * 68 + (idx & 63)] = We[idx];
    __syncthreads();

    int lane = threadIdx.x & 63;
    int tl = lane & 15;                     // edge-attr dim owned by this lane
    int hb = lane & 48;                     // head base channel
    float wcol[16];
#pragma unroll
    for (int t = 0; t < 16; ++t) wcol[t] = weS[t * 68 + lane];
    float beL = be[lane];

    int gwave  = (blockIdx.x * blockDim.x + threadIdx.x) >> 6;
    int nwaves = (gridDim.x * blockDim.x) >> 6;

    const float4* wr4 = (const float4*)(weS + tl * 68 + hb);
    float4 wa = wr4[0], wb = wr4[1], wc4 = wr4[2], wd = wr4[3];

    for (int i = gwave; i < N; i += nwaves) {
        float q = Q[(size_t)i * 64 + lane];

        // ---- per-node prologue ----
        const float4* qh4 = (const float4*)(Q + (size_t)i * 64 + hb);
        float4 qa = qh4[0], qb4 = qh4[1], qc4 = qh4[2], qd = qh4[3];
        float G = qa.x * wa.x + qa.y * wa.y + qa.z * wa.z + qa.w * wa.w
                + qb4.x * wb.x + qb4.y * wb.y + qb4.z * wb.z + qb4.w * wb.w
                + qc4.x * wc4.x + qc4.y * wc4.y + qc4.z * wc4.z + qc4.w * wc4.w
                + qd.x * wd.x + qd.y * wd.y + qd.z * wd.z + qd.w * wd.w;
        float rb = q * beL;
#pragma unroll
        for (int off = 8; off >= 1; off >>= 1) rb += __shfl_xor(rb, off, 16);
        float qbase = rb * 0.25f;

        int beg = row_start[i], end = row_start[i + 1];
        float m = -INFINITY, s = 0.f, acc = 0.f, z = 0.f;

        int p = beg;
        // ---- 8-wide pipelined main loop ----
        if (p + 7 < end) {
            // prologue prefetch: indices + edge-attr for first iteration
            int j0 = csr_src[p],     j1 = csr_src[p + 1];
            int j2 = csr_src[p + 2], j3 = csr_src[p + 3];
            int j4 = csr_src[p + 4], j5 = csr_src[p + 5];
            int j6 = csr_src[p + 6], j7 = csr_src[p + 7];
            const float* ea = csr_ea + (size_t)p * 16 + tl;
            float a0 = ea[0],  a1 = ea[16],  a2 = ea[32],  a3 = ea[48];
            float a4 = ea[64], a5 = ea[80],  a6 = ea[96],  a7 = ea[112];

            do {
                // (1) issue KV gathers for current indices
                unsigned int u0 = KVu[(size_t)j0 * 64 + lane];
                unsigned int u1 = KVu[(size_t)j1 * 64 + lane];
                unsigned int u2 = KVu[(size_t)j2 * 64 + lane];
                unsigned int u3 = KVu[(size_t)j3 * 64 + lane];
                unsigned int u4 = KVu[(size_t)j4 * 64 + lane];
                unsigned int u5 = KVu[(size_t)j5 * 64 + lane];
                unsigned int u6 = KVu[(size_t)j6 * 64 + lane];
                unsigned int u7 = KVu[(size_t)j7 * 64 + lane];

                // (2) issue NEXT iteration's index + ea loads (stay in flight)
                int pn = p + 8;
                bool more = (pn + 7 < end);      // wave-uniform
                int jn0 = j0, jn1 = j1, jn2 = j2, jn3 = j3;
                int jn4 = j4, jn5 = j5, jn6 = j6, jn7 = j7;
                float an0 = a0, an1 = a1, an2 = a2, an3 = a3;
                float an4 = a4, an5 = a5, an6 = a6, an7 = a7;
                if (more) {
                    jn0 = csr_src[pn];     jn1 = csr_src[pn + 1];
                    jn2 = csr_src[pn + 2]; jn3 = csr_src[pn + 3];
                    jn4 = csr_src[pn + 4]; jn5 = csr_src[pn + 5];
                    jn6 = csr_src[pn + 6]; jn7 = csr_src[pn + 7];
                    const float* ean = csr_ea + (size_t)pn * 16 + tl;
                    an0 = ean[0];  an1 = ean[16];  an2 = ean[32];  an3 = ean[48];
                    an4 = ean[64]; an5 = ean[80];  an6 = ean[96];  an7 = ean[112];
                }

                // (3) compute on current data (waits only on KV gathers)
                float k0, v0, k1, v1, k2, v2, k3, v3, k4, v4, k5, v5, k6, v6, k7, v7;
                KV_DECODE(u0, k0, v0)  KV_DECODE(u1, k1, v1)
                KV_DECODE(u2, k2, v2)  KV_DECODE(u3, k3, v3)
                KV_DECODE(u4, k4, v4)  KV_DECODE(u5, k5, v5)
                KV_DECODE(u6, k6, v6)  KV_DECODE(u7, k7, v7)

                float l0 = q * k0 + a0 * G;
                float l1 = q * k1 + a1 * G;
                float l2 = q * k2 + a2 * G;
                float l3 = q * k3 + a3 * G;
                float l4 = q * k4 + a4 * G;
                float l5 = q * k5 + a5 * G;
                float l6 = q * k6 + a6 * G;
                float l7 = q * k7 + a7 * G;
#pragma unroll
                for (int off = 8; off >= 1; off >>= 1) {
                    l0 += __shfl_xor(l0, off, 16);
                    l1 += __shfl_xor(l1, off, 16);
                    l2 += __shfl_xor(l2, off, 16);
                    l3 += __shfl_xor(l3, off, 16);
                    l4 += __shfl_xor(l4, off, 16);
                    l5 += __shfl_xor(l5, off, 16);
                    l6 += __shfl_xor(l6, off, 16);
                    l7 += __shfl_xor(l7, off, 16);
                }
                l0 = l0 * 0.25f + qbase;  l1 = l1 * 0.25f + qbase;
                l2 = l2 * 0.25f + qbase;  l3 = l3 * 0.25f + qbase;
                l4 = l4 * 0.25f + qbase;  l5 = l5 * 0.25f + qbase;
                l6 = l6 * 0.25f + qbase;  l7 = l7 * 0.25f + qbase;

                float nm = fmaxf(fmaxf(fmaxf(l0, l1), fmaxf(l2, l3)),
                                 fmaxf(fmaxf(l4, l5), fmaxf(l6, l7)));
                nm = fmaxf(nm, m);
                float sc = __expf(m - nm);
                float w0 = __expf(l0 - nm), w1 = __expf(l1 - nm);
                float w2 = __expf(l2 - nm), w3 = __expf(l3 - nm);
                float w4 = __expf(l4 - nm), w5 = __expf(l5 - nm);
                float w6 = __expf(l6 - nm), w7 = __expf(l7 - nm);
                s   = s * sc + ((w0 + w1) + (w2 + w3)) + ((w4 + w5) + (w6 + w7));
                acc = acc * sc + ((w0 * v0 + w1 * v1) + (w2 * v2 + w3 * v3))
                               + ((w4 * v4 + w5 * v5) + (w6 * v6 + w7 * v7));
                z   = z * sc + ((w0 * a0 + w1 * a1) + (w2 * a2 + w3 * a3))
                             + ((w4 * a4 + w5 * a5) + (w6 * a6 + w7 * a7));
                m = nm;

                // rotate pipeline registers
                j0 = jn0; j1 = jn1; j2 = jn2; j3 = jn3;
                j4 = jn4; j5 = jn5; j6 = jn6; j7 = jn7;
                a0 = an0; a1 = an1; a2 = an2; a3 = an3;
                a4 = an4; a5 = an5; a6 = an6; a7 = an7;
                p = pn;
            } while (p + 7 < end);
        }
        // ---- 4-wide tail ----
        for (; p + 3 < end; p += 4) {
            int j0 = csr_src[p],     j1 = csr_src[p + 1];
            int j2 = csr_src[p + 2], j3 = csr_src[p + 3];
            unsigned int u0 = KVu[(size_t)j0 * 64 + lane];
            unsigned int u1 = KVu[(size_t)j1 * 64 + lane];
            unsigned int u2 = KVu[(size_t)j2 * 64 + lane];
            unsigned int u3 = KVu[(size_t)j3 * 64 + lane];
            const float* ea = csr_ea + (size_t)p * 16 + tl;
            float a0 = ea[0], a1 = ea[16], a2 = ea[32], a3 = ea[48];

            float k0, v0, k1, v1, k2, v2, k3, v3;
            KV_DECODE(u0, k0, v0)  KV_DECODE(u1, k1, v1)
            KV_DECODE(u2, k2, v2)  KV_DECODE(u3, k3, v3)

            float l0 = q * k0 + a0 * G;
            float l1 = q * k1 + a1 * G;
            float l2 = q * k2 + a2 * G;
            float l3 = q * k3 + a3 * G;
#pragma unroll
            for (int off = 8; off >= 1; off >>= 1) {
                l0 += __shfl_xor(l0, off, 16);
                l1 += __shfl_xor(l1, off, 16);
                l2 += __shfl_xor(l2, off, 16);
                l3 += __shfl_xor(l3, off, 16);
            }
            l0 = l0 * 0.25f + qbase;  l1 = l1 * 0.25f + qbase;
            l2 = l2 * 0.25f + qbase;  l3 = l3 * 0.25f + qbase;

            float nm = fmaxf(fmaxf(fmaxf(l0, l1), fmaxf(l2, l3)), m);
            float sc = __expf(m - nm);
            float w0 = __expf(l0 - nm), w1 = __expf(l1 - nm);
            float w2 = __expf(l2 - nm), w3 = __expf(l3 - nm);
            s   = s * sc + w0 + w1 + w2 + w3;
            acc = acc * sc + w0 * v0 + w1 * v1 + w2 * v2 + w3 * v3;
            z   = z * sc + w0 * a0 + w1 * a1 + w2 * a2 + w3 * a3;
            m = nm;
        }
        // ---- scalar tail ----
        for (; p < end; ++p) {
            int j = csr_src[p];
            unsigned int u = KVu[(size_t)j * 64 + lane];
            float a = csr_ea[(size_t)p * 16 + tl];
            float kf, vf;
            KV_DECODE(u, kf, vf)
            float l = q * kf + a * G;
#pragma unroll
            for (int off = 8; off >= 1; off >>= 1) l += __shfl_xor(l, off, 16);
            l = l * 0.25f + qbase;
            float nm = fmaxf(m, l);
            float sc = __expf(m - nm);
            float w  = __expf(l - nm);
            s   = s * sc + w;
            acc = acc * sc + w * vf;
            z   = z * sc + w * a;
            m = nm;
        }

        // ---- epilogue: fold edge-projection back in ----
        float o;
        if (s > 0.f) {
            float t = acc;
#pragma unroll
            for (int u = 0; u < 16; ++u) t += wcol[u] * __shfl(z, u, 16);
            o = t / s + beL + Ssk[(size_t)i * 64 + lane];
        } else {
            o = Ssk[(size_t)i * 64 + lane];
        }
        if (doRelu) o = fmaxf(o, 0.f);
        Hout[(size_t)i * 64 + lane] = o;
    }
}

// ---------------------------------------------------------------------------
// Fallback attention (direct algorithm) — only if ws can't hold csr_ea.
// ---------------------------------------------------------------------------
__global__ __launch_bounds__(256) void attn_k(
    const float* __restrict__ Q, const unsigned int* __restrict__ KVu,
    const float* __restrict__ Ssk,
    const int* __restrict__ row_start, const int* __restrict__ csr,
    const int* __restrict__ srcA, const float* __restrict__ edge_attr,
    const float* __restrict__ We, const float* __restrict__ be,
    float* __restrict__ Hout, int N, int doRelu)
{
    int lane = threadIdx.x & 63;
    float wcol[16];
#pragma unroll
    for (int t = 0; t < 16; ++t) wcol[t] = We[t * 64 + lane];
    float beL = be[lane];

    int gwave  = (blockIdx.x * blockDim.x + threadIdx.x) >> 6;
    int nwaves = (gridDim.x * blockDim.x) >> 6;

    for (int i = gwave; i < N; i += nwaves) {
        float q = Q[(size_t)i * 64 + lane];
        int beg = row_start[i], end = row_start[i + 1];
        float m = -INFINITY, s = 0.f, acc = 0.f;
        for (int p = beg; p < end; ++p) {
            int e = csr[p];
            int j = srcA[e];
            const float4* ap = (const float4*)(edge_attr + (size_t)e * 16);
            float4 a0 = ap[0], a1 = ap[1], a2 = ap[2], a3 = ap[3];
            unsigned int u = KVu[(size_t)j * 64 + lane];
            float kf, vf;
            KV_DECODE(u, kf, vf)
            float ea = beL;
            ea += a0.x * wcol[0]  + a0.y * wcol[1]  + a0.z * wcol[2]  + a0.w * wcol[3];
            ea += a1.x * wcol[4]  + a1.y * wcol[5]  + a1.z * wcol[6]  + a1.w * wcol[7];
            ea += a2.x * wcol[8]  + a2.y * wcol[9]  + a2.z * wcol[10] + a2.w * wcol[11];
            ea += a3.x * wcol[12] + a3.y * wcol[13] + a3.z * wcol[14] + a3.w * wcol[15];
            float kv = kf + ea, vv = vf + ea;
            float part = q * kv;
#pragma unroll
            for (int off = 8; off >= 1; off >>= 1) part += __shfl_xor(part, off, 16);
            float logit = part * 0.25f;
            float nm = fmaxf(m, logit);
            float sc = __expf(m - nm);
            float w  = __expf(logit - nm);
            s = s * sc + w;  acc = acc * sc + w * vv;  m = nm;
        }
        float agg = (s > 0.f) ? acc / s : 0.f;
        float o = agg + Ssk[(size_t)i * 64 + lane];
        if (doRelu) o = fmaxf(o, 0.f);
        Hout[(size_t)i * 64 + lane] = o;
    }
}

// ---------------------------------------------------------------------------
// Deterministic global mean pool (verified R9): one block per graph,
// binary-searched boundaries, fixed-order LDS combine, no atomics.
// ---------------------------------------------------------------------------
__device__ __forceinline__ int lbound(const int* __restrict__ a, int n, int key) {
    int lo = 0, hi = n;
    while (lo < hi) { int mid = (lo + hi) >> 1; if (a[mid] < key) lo = mid + 1; else hi = mid; }
    return lo;
}

__global__ __launch_bounds__(256) void pool_mean_k(
    const float* __restrict__ H, const int* __restrict__ batch,
    float* __restrict__ pooled, int N)
{
    int g = blockIdx.x;
    int lo = lbound(batch, N, g);
    int hi = lbound(batch, N, g + 1);
    int lane = threadIdx.x & 63;
    int w = threadIdx.x >> 6;

    float acc = 0.f;
    for (int i = lo + w; i < hi; i += 4)
        acc += H[(size_t)i * 64 + lane];

    __shared__ float part[4][64];
    part[w][lane] = acc;
    __syncthreads();
    if (w == 0) {
        float s = ((part[0][lane] + part[1][lane]) + part[2][lane]) + part[3][lane];
        float cnt = (float)(hi - lo);
        pooled[g * 64 + lane] = s / fmaxf(cnt, 1.0f);
    }
}

__global__ __launch_bounds__(64) void mlp_k(
    const float* __restrict__ pooled,      // means
    const float* __restrict__ lin1_w, const float* __restrict__ lin1_b,
    const float* __restrict__ lin2_w, const float* __restrict__ lin2_b,
    float* __restrict__ out)
{
    int g = blockIdx.x;
    int c = threadIdx.x;
    float acc = lin1_b[c];
#pragma unroll
    for (int t = 0; t < 64; ++t) acc += pooled[g * 64 + t] * lin1_w[t * 64 + c];
    float r = fmaxf(acc, 0.f) * lin2_w[c];
#pragma unroll
    for (int off = 32; off >= 1; off >>= 1) r += __shfl_xor(r, off, 64);
    if (c == 0) out[g] = r + lin2_b[0];
}

// ---------------------------------------------------------------------------
extern "C" void kernel_launch(void* const* d_in, const int* in_sizes, int n_in,
                              void* d_out, int out_size, void* d_ws, size_t ws_size,
                              hipStream_t stream) {
    const float* x        = (const float*)d_in[0];
    const int*   eidx     = (const int*)  d_in[1];
    const float* eattr    = (const float*)d_in[2];
    const int*   batch    = (const int*)  d_in[3];
    const float* Wq       = (const float*)d_in[4];
    const float* bq       = (const float*)d_in[5];
    const float* Wk       = (const float*)d_in[6];
    const float* bk       = (const float*)d_in[7];
    const float* Wv       = (const float*)d_in[8];
    const float* bv       = (const float*)d_in[9];
    const float* We       = (const float*)d_in[10];
    const float* be       = (const float*)d_in[11];
    const float* Wskip    = (const float*)d_in[12];
    const float* bskip    = (const float*)d_in[13];
    const float* lin1_w   = (const float*)d_in[14];
    const float* lin1_b   = (const float*)d_in[15];
    const float* lin2_w   = (const float*)d_in[16];
    const float* lin2_b   = (const float*)d_in[17];

    int N = in_sizes[0] / 64;
    int E = in_sizes[1] / 2;
    const int* src = eidx;
    const int* dst = eidx + E;

    // workspace layout
    char* w = (char*)d_ws;
    auto alloc = [&](size_t bytes) {
        char* p = w;
        w += (bytes + 255) & ~(size_t)255;
        return p;
    };
    float* Q   = (float*)alloc((size_t)N * 64 * 4);
    unsigned short* KVh = (unsigned short*)alloc((size_t)N * 128 * 2);  // bf16 {K,V} pairs
    float* S   = (float*)alloc((size_t)N * 64 * 4);
    float* H   = (float*)alloc((size_t)N * 64 * 4);
    // deg and cursor adjacent -> single memset covers both
    int* deg       = (int*)alloc((size_t)N * 4);
    int* cursor    = (int*)alloc((size_t)N * 4);
    int* row_start = (int*)alloc((size_t)(N + 1) * 4);
    int* csr       = (int*)alloc((size_t)E * 4);
    int* chunkSums = (int*)alloc(128 * 4);
    float* pooled  = (float*)alloc(128 * 64 * 4);
    // fast-path extras (checked against ws_size)
    int*    csr_src = (int*)   alloc((size_t)E * 4);
    float4* csr_ea  = (float4*)alloc((size_t)E * 16 * 4);
    bool pre = ((size_t)(w - (char*)d_ws) <= ws_size);

    // one memset over deg..cursor (adjacent)
    hipMemsetAsync(deg, 0, (size_t)((char*)cursor - (char*)deg) + (size_t)N * 4, stream);

    // CSR build
    count_k<<<(E + 255) / 256, 256, 0, stream>>>(dst, E, deg);
    int nChunks = (N + 1023) / 1024;
    scan_chunk<<<nChunks, 1024, 0, stream>>>(deg, row_start, chunkSums, N);
    scan_sums<<<1, 128, 0, stream>>>(chunkSums, nChunks);
    scan_add<<<(N + 255) / 256, 256, 0, stream>>>(row_start, chunkSums, N, E);
    fill_k<<<(E + 255) / 256, 256, 0, stream>>>(dst, E, row_start, cursor, csr);
    // determinism: fix within-row order (atomic fill order is race-dependent)
    sort_rows_k<<<(N + 255) / 256, 256, 0, stream>>>(row_start, csr, N);

    // one-time edge-data permutation into CSR order
    if (pre) {
        gather_edges<<<((size_t)E * 4 + 255) / 256, 256, 0, stream>>>(
            csr, src, (const float4*)eattr, csr_src, csr_ea, E);
    }

    // 3 transformer layers
    const float* Hin = x;
    for (int l = 0; l < 3; ++l) {
        gemm_qkvs<<<1024, 256, 0, stream>>>(Hin,
            Wq + l * 4096, bq + l * 64, Wk + l * 4096, bk + l * 64,
            Wv + l * 4096, bv + l * 64, Wskip + l * 4096, bskip + l * 64,
            Q, KVh, S, N);
        if (pre) {
            attn_pre<<<4096, 256, 0, stream>>>(Q, (const unsigned int*)KVh, S,
                row_start, csr_src, (const float*)csr_ea,
                We + l * 1024, be + l * 64, H, N, (l < 2) ? 1 : 0);
        } else {
            attn_k<<<4096, 256, 0, stream>>>(Q, (const unsigned int*)KVh, S,
                row_start, csr, src, eattr,
                We + l * 1024, be + l * 64, H, N, (l < 2) ? 1 : 0);
        }
        Hin = H;
    }

    // deterministic pool + head
    pool_mean_k<<<128, 256, 0, stream>>>(Hin, batch, pooled, N);
    mlp_k<<<128, 64, 0, stream>>>(pooled, lin1_w, lin1_b, lin2_w, lin2_b,
                                  (float*)d_out);
}

// Round 13
// 977.762 us; speedup vs baseline: 1.0016x; 1.0016x over previous
//
#include <hip/hip_runtime.h>
#include <hip/hip_bf16.h>

#define NODES_C 64
#define HEADS 4
#define HEAD_D 16

// f32 -> bf16 with round-to-nearest-even (deterministic, branch-free)
__device__ __forceinline__ unsigned short f32_to_bf16(float f) {
    unsigned int x = __float_as_uint(f);
    unsigned int r = x + 0x7fffu + ((x >> 16) & 1u);
    return (unsigned short)(r >> 16);
}

// ---------------------------------------------------------------------------
// CSR build
// ---------------------------------------------------------------------------
__global__ void count_k(const int* __restrict__ dst, int E, int* __restrict__ deg) {
    int e = blockIdx.x * blockDim.x + threadIdx.x;
    if (e < E) atomicAdd(&deg[dst[e]], 1);
}

__global__ __launch_bounds__(1024) void scan_chunk(const int* __restrict__ deg,
                                                   int* __restrict__ excl,
                                                   int* __restrict__ chunkSums, int N) {
    __shared__ int buf[1024];
    int i = blockIdx.x * 1024 + threadIdx.x;
    int v = (i < N) ? deg[i] : 0;
    buf[threadIdx.x] = v;
    __syncthreads();
    for (int off = 1; off < 1024; off <<= 1) {
        int t = (threadIdx.x >= off) ? buf[threadIdx.x - off] : 0;
        __syncthreads();
        buf[threadIdx.x] += t;
        __syncthreads();
    }
    if (i < N) excl[i] = buf[threadIdx.x] - v;   // exclusive within chunk
    if (threadIdx.x == 1023) chunkSums[blockIdx.x] = buf[1023];
}

__global__ __launch_bounds__(128) void scan_sums(int* __restrict__ chunkSums, int nChunks) {
    __shared__ int buf[128];
    int v = (threadIdx.x < nChunks) ? chunkSums[threadIdx.x] : 0;
    buf[threadIdx.x] = v;
    __syncthreads();
    for (int off = 1; off < 128; off <<= 1) {
        int t = (threadIdx.x >= off) ? buf[threadIdx.x - off] : 0;
        __syncthreads();
        buf[threadIdx.x] += t;
        __syncthreads();
    }
    if (threadIdx.x < nChunks) chunkSums[threadIdx.x] = buf[threadIdx.x] - v;  // exclusive
}

__global__ void scan_add(int* __restrict__ excl, const int* __restrict__ chunkSums,
                         int N, int E) {
    int i = blockIdx.x * blockDim.x + threadIdx.x;
    if (i < N) excl[i] += chunkSums[i >> 10];
    if (i == 0) excl[N] = E;
}

__global__ void fill_k(const int* __restrict__ dst, int E,
                       const int* __restrict__ row_start, int* __restrict__ cursor,
                       int* __restrict__ csr) {
    int e = blockIdx.x * blockDim.x + threadIdx.x;
    if (e < E) {
        int d = dst[e];
        int pos = atomicAdd(&cursor[d], 1);
        csr[row_start[d] + pos] = e;
    }
}

// ---------------------------------------------------------------------------
// DETERMINISM (verified R9): sort each CSR row by edge id so the atomic
// fill order doesn't leak into f32 summation order. One thread per row.
// ---------------------------------------------------------------------------
__global__ void sort_rows_k(const int* __restrict__ row_start, int* __restrict__ csr,
                            int N) {
    int i = blockIdx.x * blockDim.x + threadIdx.x;
    if (i >= N) return;
    int beg = row_start[i], end = row_start[i + 1];
    for (int p = beg + 1; p < end; ++p) {
        int key = csr[p];
        int j = p - 1;
        while (j >= beg && csr[j] > key) { csr[j + 1] = csr[j]; --j; }
        csr[j + 1] = key;
    }
}

// ---------------------------------------------------------------------------
// One-time edge-data permutation into CSR order.
// ---------------------------------------------------------------------------
__global__ void gather_edges(const int* __restrict__ csr, const int* __restrict__ srcA,
                             const float4* __restrict__ ea4,
                             int* __restrict__ csr_src, float4* __restrict__ csr_ea,
                             int E) {
    int t = blockIdx.x * blockDim.x + threadIdx.x;
    int p = t >> 2, q = t & 3;
    if (p < E) {
        int e = csr[p];
        if (q == 0) csr_src[p] = srcA[e];
        csr_ea[(size_t)p * 4 + q] = ea4[(size_t)e * 4 + q];
    }
}

// ---------------------------------------------------------------------------
// Fused node projections, 2-COLUMN REGISTER TILE (R13): each thread owns one
// column of TWO weight matrices (group 0: Wq+Wk, group 1: Wv+Ws), so every
// LDS b128 read of h feeds 8 FMA instead of 4 — halves LDS-pipe pressure
// (theory: the old kernel was LDS-issue-bound, not VALU-bound).
// K/V stored as BF16 PAIRS: KVh[n*128+2c]={K}, [..+1]={V} (verified R11).
// ---------------------------------------------------------------------------
#define GB 16
__global__ __launch_bounds__(128) void gemm_qkvs(
    const float* __restrict__ Hin,
    const float* __restrict__ Wq, const float* __restrict__ bq,
    const float* __restrict__ Wk, const float* __restrict__ bk,
    const float* __restrict__ Wv, const float* __restrict__ bv,
    const float* __restrict__ Ws, const float* __restrict__ bs,
    float* __restrict__ Q, unsigned short* __restrict__ KVh,
    float* __restrict__ Ssk, int N)
{
    int g = threadIdx.x >> 6;          // 0: Q+K, 1: V+S
    int c = threadIdx.x & 63;
    const float* W1 = (g == 0) ? Wq : Wv;
    const float* b1 = (g == 0) ? bq : bv;
    const float* W2 = (g == 0) ? Wk : Ws;
    const float* b2 = (g == 0) ? bk : bs;

    float w1[64], w2[64];
#pragma unroll
    for (int t = 0; t < 64; ++t) {
        w1[t] = W1[t * 64 + c];
        w2[t] = W2[t * 64 + c];
    }
    float bias1 = b1[c], bias2 = b2[c];

    __shared__ __align__(16) float hrow[GB][64];

    for (int base = blockIdx.x * GB; base < N; base += gridDim.x * GB) {
        int nn = min(GB, N - base);
        __syncthreads();
        for (int idx = threadIdx.x; idx < nn * 64; idx += 128)
            hrow[idx >> 6][idx & 63] = Hin[base * 64 + idx];
        __syncthreads();
        for (int r = 0; r < nn; ++r) {
            const float4* h4 = (const float4*)hrow[r];
            float acc1 = bias1, acc2 = bias2;
#pragma unroll
            for (int t4 = 0; t4 < 16; ++t4) {
                float4 hv = h4[t4];
                acc1 += hv.x * w1[4 * t4 + 0];
                acc1 += hv.y * w1[4 * t4 + 1];
                acc1 += hv.z * w1[4 * t4 + 2];
                acc1 += hv.w * w1[4 * t4 + 3];
                acc2 += hv.x * w2[4 * t4 + 0];
                acc2 += hv.y * w2[4 * t4 + 1];
                acc2 += hv.z * w2[4 * t4 + 2];
                acc2 += hv.w * w2[4 * t4 + 3];
            }
            size_t row = (size_t)(base + r);
            if (g == 0) {                                  // wave-uniform
                Q[row * 64 + c] = acc1;                    // Q  (f32)
                KVh[row * 128 + 2 * c] = f32_to_bf16(acc2);// K  (bf16)
            } else {
                KVh[row * 128 + 2 * c + 1] = f32_to_bf16(acc1); // V (bf16)
                Ssk[row * 64 + c] = acc2;                  // S  (f32)
            }
        }
    }
}

// ---------------------------------------------------------------------------
// Edge-softmax attention, bf16 KV + pipelined prefetch (R11/R12 — at its
// structural floor per R10/R11/R12 counters; unchanged this round).
// ---------------------------------------------------------------------------
#define KV_DECODE(u, kf, vf)                                \
    kf = __uint_as_float((u) << 16);                        \
    vf = __uint_as_float((u) & 0xffff0000u);

__global__ __launch_bounds__(256) void attn_pre(
    const float* __restrict__ Q, const unsigned int* __restrict__ KVu,
    const float* __restrict__ Ssk,
    const int* __restrict__ row_start, const int* __restrict__ csr_src,
    const float* __restrict__ csr_ea,      // [E][16], CSR order
    const float* __restrict__ We, const float* __restrict__ be,
    float* __restrict__ Hout, int N, int doRelu)
{
    __shared__ float weS[16 * 68];          // padded rows
    for (int idx = threadIdx.x; idx < 1024; idx += 256)
        weS[(idx >> 6) * 68 + (idx & 63)] = We[idx];
    __syncthreads();

    int lane = threadIdx.x & 63;
    int tl = lane & 15;                     // edge-attr dim owned by this lane
    int hb = lane & 48;                     // head base channel
    float wcol[16];
#pragma unroll
    for (int t = 0; t < 16; ++t) wcol[t] = weS[t * 68 + lane];
    float beL = be[lane];

    int gwave  = (blockIdx.x * blockDim.x + threadIdx.x) >> 6;
    int nwaves = (gridDim.x * blockDim.x) >> 6;

    const float4* wr4 = (const float4*)(weS + tl * 68 + hb);
    float4 wa = wr4[0], wb = wr4[1], wc4 = wr4[2], wd = wr4[3];

    for (int i = gwave; i < N; i += nwaves) {
        float q = Q[(size_t)i * 64 + lane];

        // ---- per-node prologue ----
        const float4* qh4 = (const float4*)(Q + (size_t)i * 64 + hb);
        float4 qa = qh4[0], qb4 = qh4[1], qc4 = qh4[2], qd = qh4[3];
        float G = qa.x * wa.x + qa.y * wa.y + qa.z * wa.z + qa.w * wa.w
                + qb4.x * wb.x + qb4.y * wb.y + qb4.z * wb.z + qb4.w * wb.w
                + qc4.x * wc4.x + qc4.y * wc4.y + qc4.z * wc4.z + qc4.w * wc4.w
                + qd.x * wd.x + qd.y * wd.y + qd.z * wd.z + qd.w * wd.w;
        float rb = q * beL;
#pragma unroll
        for (int off = 8; off >= 1; off >>= 1) rb += __shfl_xor(rb, off, 16);
        float qbase = rb * 0.25f;

        int beg = row_start[i], end = row_start[i + 1];
        float m = -INFINITY, s = 0.f, acc = 0.f, z = 0.f;

        int p = beg;
        // ---- 8-wide pipelined main loop ----
        if (p + 7 < end) {
            int j0 = csr_src[p],     j1 = csr_src[p + 1];
            int j2 = csr_src[p + 2], j3 = csr_src[p + 3];
            int j4 = csr_src[p + 4], j5 = csr_src[p + 5];
            int j6 = csr_src[p + 6], j7 = csr_src[p + 7];
            const float* ea = csr_ea + (size_t)p * 16 + tl;
            float a0 = ea[0],  a1 = ea[16],  a2 = ea[32],  a3 = ea[48];
            float a4 = ea[64], a5 = ea[80],  a6 = ea[96],  a7 = ea[112];

            do {
                unsigned int u0 = KVu[(size_t)j0 * 64 + lane];
                unsigned int u1 = KVu[(size_t)j1 * 64 + lane];
                unsigned int u2 = KVu[(size_t)j2 * 64 + lane];
                unsigned int u3 = KVu[(size_t)j3 * 64 + lane];
                unsigned int u4 = KVu[(size_t)j4 * 64 + lane];
                unsigned int u5 = KVu[(size_t)j5 * 64 + lane];
                unsigned int u6 = KVu[(size_t)j6 * 64 + lane];
                unsigned int u7 = KVu[(size_t)j7 * 64 + lane];

                int pn = p + 8;
                bool more = (pn + 7 < end);      // wave-uniform
                int jn0 = j0, jn1 = j1, jn2 = j2, jn3 = j3;
                int jn4 = j4, jn5 = j5, jn6 = j6, jn7 = j7;
                float an0 = a0, an1 = a1, an2 = a2, an3 = a3;
                float an4 = a4, an5 = a5, an6 = a6, an7 = a7;
                if (more) {
                    jn0 = csr_src[pn];     jn1 = csr_src[pn + 1];
                    jn2 = csr_src[pn + 2]; jn3 = csr_src[pn + 3];
                    jn4 = csr_src[pn + 4]; jn5 = csr_src[pn + 5];
                    jn6 = csr_src[pn + 6]; jn7 = csr_src[pn + 7];
                    const float* ean = csr_ea + (size_t)pn * 16 + tl;
                    an0 = ean[0];  an1 = ean[16];  an2 = ean[32];  an3 = ean[48];
                    an4 = ean[64]; an5 = ean[80];  an6 = ean[96];  an7 = ean[112];
                }

                float k0, v0, k1, v1, k2, v2, k3, v3, k4, v4, k5, v5, k6, v6, k7, v7;
                KV_DECODE(u0, k0, v0)  KV_DECODE(u1, k1, v1)
                KV_DECODE(u2, k2, v2)  KV_DECODE(u3, k3, v3)
                KV_DECODE(u4, k4, v4)  KV_DECODE(u5, k5, v5)
                KV_DECODE(u6, k6, v6)  KV_DECODE(u7, k7, v7)

                float l0 = q * k0 + a0 * G;
                float l1 = q * k1 + a1 * G;
                float l2 = q * k2 + a2 * G;
                float l3 = q * k3 + a3 * G;
                float l4 = q * k4 + a4 * G;
                float l5 = q * k5 + a5 * G;
                float l6 = q * k6 + a6 * G;
                float l7 = q * k7 + a7 * G;
#pragma unroll
                for (int off = 8; off >= 1; off >>= 1) {
                    l0 += __shfl_xor(l0, off, 16);
                    l1 += __shfl_xor(l1, off, 16);
                    l2 += __shfl_xor(l2, off, 16);
                    l3 += __shfl_xor(l3, off, 16);
                    l4 += __shfl_xor(l4, off, 16);
                    l5 += __shfl_xor(l5, off, 16);
                    l6 += __shfl_xor(l6, off, 16);
                    l7 += __shfl_xor(l7, off, 16);
                }
                l0 = l0 * 0.25f + qbase;  l1 = l1 * 0.25f + qbase;
                l2 = l2 * 0.25f + qbase;  l3 = l3 * 0.25f + qbase;
                l4 = l4 * 0.25f + qbase;  l5 = l5 * 0.25f + qbase;
                l6 = l6 * 0.25f + qbase;  l7 = l7 * 0.25f + qbase;

                float nm = fmaxf(fmaxf(fmaxf(l0, l1), fmaxf(l2, l3)),
                                 fmaxf(fmaxf(l4, l5), fmaxf(l6, l7)));
                nm = fmaxf(nm, m);
                float sc = __expf(m - nm);
                float w0 = __expf(l0 - nm), w1 = __expf(l1 - nm);
                float w2 = __expf(l2 - nm), w3 = __expf(l3 - nm);
                float w4 = __expf(l4 - nm), w5 = __expf(l5 - nm);
                float w6 = __expf(l6 - nm), w7 = __expf(l7 - nm);
                s   = s * sc + ((w0 + w1) + (w2 + w3)) + ((w4 + w5) + (w6 + w7));
                acc = acc * sc + ((w0 * v0 + w1 * v1) + (w2 * v2 + w3 * v3))
                               + ((w4 * v4 + w5 * v5) + (w6 * v6 + w7 * v7));
                z   = z * sc + ((w0 * a0 + w1 * a1) + (w2 * a2 + w3 * a3))
                             + ((w4 * a4 + w5 * a5) + (w6 * a6 + w7 * a7));
                m = nm;

                j0 = jn0; j1 = jn1; j2 = jn2; j3 = jn3;
                j4 = jn4; j5 = jn5; j6 = jn6; j7 = jn7;
                a0 = an0; a1 = an1; a2 = an2; a3 = an3;
                a4 = an4; a5 = an5; a6 = an6; a7 = an7;
                p = pn;
            } while (p + 7 < end);
        }
        // ---- 4-wide tail ----
        for (; p + 3 < end; p += 4) {
            int j0 = csr_src[p],     j1 = csr_src[p + 1];
            int j2 = csr_src[p + 2], j3 = csr_src[p + 3];
            unsigned int u0 = KVu[(size_t)j0 * 64 + lane];
            unsigned int u1 = KVu[(size_t)j1 * 64 + lane];
            unsigned int u2 = KVu[(size_t)j2 * 64 + lane];
            unsigned int u3 = KVu[(size_t)j3 * 64 + lane];
            const float* ea = csr_ea + (size_t)p * 16 + tl;
            float a0 = ea[0], a1 = ea[16], a2 = ea[32], a3 = ea[48];

            float k0, v0, k1, v1, k2, v2, k3, v3;
            KV_DECODE(u0, k0, v0)  KV_DECODE(u1, k1, v1)
            KV_DECODE(u2, k2, v2)  KV_DECODE(u3, k3, v3)

            float l0 = q * k0 + a0 * G;
            float l1 = q * k1 + a1 * G;
            float l2 = q * k2 + a2 * G;
            float l3 = q * k3 + a3 * G;
#pragma unroll
            for (int off = 8; off >= 1; off >>= 1) {
                l0 += __shfl_xor(l0, off, 16);
                l1 += __shfl_xor(l1, off, 16);
                l2 += __shfl_xor(l2, off, 16);
                l3 += __shfl_xor(l3, off, 16);
            }
            l0 = l0 * 0.25f + qbase;  l1 = l1 * 0.25f + qbase;
            l2 = l2 * 0.25f + qbase;  l3 = l3 * 0.25f + qbase;

            float nm = fmaxf(fmaxf(fmaxf(l0, l1), fmaxf(l2, l3)), m);
            float sc = __expf(m - nm);
            float w0 = __expf(l0 - nm), w1 = __expf(l1 - nm);
            float w2 = __expf(l2 - nm), w3 = __expf(l3 - nm);
            s   = s * sc + w0 + w1 + w2 + w3;
            acc = acc * sc + w0 * v0 + w1 * v1 + w2 * v2 + w3 * v3;
            z   = z * sc + w0 * a0 + w1 * a1 + w2 * a2 + w3 * a3;
            m = nm;
        }
        // ---- scalar tail ----
        for (; p < end; ++p) {
            int j = csr_src[p];
            unsigned int u = KVu[(size_t)j * 64 + lane];
            float a = csr_ea[(size_t)p * 16 + tl];
            float kf, vf;
            KV_DECODE(u, kf, vf)
            float l = q * kf + a * G;
#pragma unroll
            for (int off = 8; off >= 1; off >>= 1) l += __shfl_xor(l, off, 16);
            l = l * 0.25f + qbase;
            float nm = fmaxf(m, l);
            float sc = __expf(m - nm);
            float w  = __expf(l - nm);
            s   = s * sc + w;
            acc = acc * sc + w * vf;
            z   = z * sc + w * a;
            m = nm;
        }

        // ---- epilogue: fold edge-projection back in ----
        float o;
        if (s > 0.f) {
            float t = acc;
#pragma unroll
            for (int u = 0; u < 16; ++u) t += wcol[u] * __shfl(z, u, 16);
            o = t / s + beL + Ssk[(size_t)i * 64 + lane];
        } else {
            o = Ssk[(size_t)i * 64 + lane];
        }
        if (doRelu) o = fmaxf(o, 0.f);
        Hout[(size_t)i * 64 + lane] = o;
    }
}

// ---------------------------------------------------------------------------
// Fallback attention (direct algorithm) — only if ws can't hold csr_ea.
// ---------------------------------------------------------------------------
__global__ __launch_bounds__(256) void attn_k(
    const float* __restrict__ Q, const unsigned int* __restrict__ KVu,
    const float* __restrict__ Ssk,
    const int* __restrict__ row_start, const int* __restrict__ csr,
    const int* __restrict__ srcA, const float* __restrict__ edge_attr,
    const float* __restrict__ We, const float* __restrict__ be,
    float* __restrict__ Hout, int N, int doRelu)
{
    int lane = threadIdx.x & 63;
    float wcol[16];
#pragma unroll
    for (int t = 0; t < 16; ++t) wcol[t] = We[t * 64 + lane];
    float beL = be[lane];

    int gwave  = (blockIdx.x * blockDim.x + threadIdx.x) >> 6;
    int nwaves = (gridDim.x * blockDim.x) >> 6;

    for (int i = gwave; i < N; i += nwaves) {
        float q = Q[(size_t)i * 64 + lane];
        int beg = row_start[i], end = row_start[i + 1];
        float m = -INFINITY, s = 0.f, acc = 0.f;
        for (int p = beg; p < end; ++p) {
            int e = csr[p];
            int j = srcA[e];
            const float4* ap = (const float4*)(edge_attr + (size_t)e * 16);
            float4 a0 = ap[0], a1 = ap[1], a2 = ap[2], a3 = ap[3];
            unsigned int u = KVu[(size_t)j * 64 + lane];
            float kf, vf;
            KV_DECODE(u, kf, vf)
            float ea = beL;
            ea += a0.x * wcol[0]  + a0.y * wcol[1]  + a0.z * wcol[2]  + a0.w * wcol[3];
            ea += a1.x * wcol[4]  + a1.y * wcol[5]  + a1.z * wcol[6]  + a1.w * wcol[7];
            ea += a2.x * wcol[8]  + a2.y * wcol[9]  + a2.z * wcol[10] + a2.w * wcol[11];
            ea += a3.x * wcol[12] + a3.y * wcol[13] + a3.z * wcol[14] + a3.w * wcol[15];
            float kv = kf + ea, vv = vf + ea;
            float part = q * kv;
#pragma unroll
            for (int off = 8; off >= 1; off >>= 1) part += __shfl_xor(part, off, 16);
            float logit = part * 0.25f;
            float nm = fmaxf(m, logit);
            float sc = __expf(m - nm);
            float w  = __expf(logit - nm);
            s = s * sc + w;  acc = acc * sc + w * vv;  m = nm;
        }
        float agg = (s > 0.f) ? acc / s : 0.f;
        float o = agg + Ssk[(size_t)i * 64 + lane];
        if (doRelu) o = fmaxf(o, 0.f);
        Hout[(size_t)i * 64 + lane] = o;
    }
}

// ---------------------------------------------------------------------------
// Deterministic global mean pool (verified R9): one block per graph,
// binary-searched boundaries, fixed-order LDS combine, no atomics.
// ---------------------------------------------------------------------------
__device__ __forceinline__ int lbound(const int* __restrict__ a, int n, int key) {
    int lo = 0, hi = n;
    while (lo < hi) { int mid = (lo + hi) >> 1; if (a[mid] < key) lo = mid + 1; else hi = mid; }
    return lo;
}

__global__ __launch_bounds__(256) void pool_mean_k(
    const float* __restrict__ H, const int* __restrict__ batch,
    float* __restrict__ pooled, int N)
{
    int g = blockIdx.x;
    int lo = lbound(batch, N, g);
    int hi = lbound(batch, N, g + 1);
    int lane = threadIdx.x & 63;
    int w = threadIdx.x >> 6;

    float acc = 0.f;
    for (int i = lo + w; i < hi; i += 4)
        acc += H[(size_t)i * 64 + lane];

    __shared__ float part[4][64];
    part[w][lane] = acc;
    __syncthreads();
    if (w == 0) {
        float s = ((part[0][lane] + part[1][lane]) + part[2][lane]) + part[3][lane];
        float cnt = (float)(hi - lo);
        pooled[g * 64 + lane] = s / fmaxf(cnt, 1.0f);
    }
}

__global__ __launch_bounds__(64) void mlp_k(
    const float* __restrict__ pooled,      // means
    const float* __restrict__ lin1_w, const float* __restrict__ lin1_b,
    const float* __restrict__ lin2_w, const float* __restrict__ lin2_b,
    float* __restrict__ out)
{
    int g = blockIdx.x;
    int c = threadIdx.x;
    float acc = lin1_b[c];
#pragma unroll
    for (int t = 0; t < 64; ++t) acc += pooled[g * 64 + t] * lin1_w[t * 64 + c];
    float r = fmaxf(acc, 0.f) * lin2_w[c];
#pragma unroll
    for (int off = 32; off >= 1; off >>= 1) r += __shfl_xor(r, off, 64);
    if (c == 0) out[g] = r + lin2_b[0];
}

// ---------------------------------------------------------------------------
extern "C" void kernel_launch(void* const* d_in, const int* in_sizes, int n_in,
                              void* d_out, int out_size, void* d_ws, size_t ws_size,
                              hipStream_t stream) {
    const float* x        = (const float*)d_in[0];
    const int*   eidx     = (const int*)  d_in[1];
    const float* eattr    = (const float*)d_in[2];
    const int*   batch    = (const int*)  d_in[3];
    const float* Wq       = (const float*)d_in[4];
    const float* bq       = (const float*)d_in[5];
    const float* Wk       = (const float*)d_in[6];
    const float* bk       = (const float*)d_in[7];
    const float* Wv       = (const float*)d_in[8];
    const float* bv       = (const float*)d_in[9];
    const float* We       = (const float*)d_in[10];
    const float* be       = (const float*)d_in[11];
    const float* Wskip    = (const float*)d_in[12];
    const float* bskip    = (const float*)d_in[13];
    const float* lin1_w   = (const float*)d_in[14];
    const float* lin1_b   = (const float*)d_in[15];
    const float* lin2_w   = (const float*)d_in[16];
    const float* lin2_b   = (const float*)d_in[17];

    int N = in_sizes[0] / 64;
    int E = in_sizes[1] / 2;
    const int* src = eidx;
    const int* dst = eidx + E;

    // workspace layout
    char* w = (char*)d_ws;
    auto alloc = [&](size_t bytes) {
        char* p = w;
        w += (bytes + 255) & ~(size_t)255;
        return p;
    };
    float* Q   = (float*)alloc((size_t)N * 64 * 4);
    unsigned short* KVh = (unsigned short*)alloc((size_t)N * 128 * 2);  // bf16 {K,V} pairs
    float* S   = (float*)alloc((size_t)N * 64 * 4);
    float* H   = (float*)alloc((size_t)N * 64 * 4);
    // deg and cursor adjacent -> single memset covers both
    int* deg       = (int*)alloc((size_t)N * 4);
    int* cursor    = (int*)alloc((size_t)N * 4);
    int* row_start = (int*)alloc((size_t)(N + 1) * 4);
    int* csr       = (int*)alloc((size_t)E * 4);
    int* chunkSums = (int*)alloc(128 * 4);
    float* pooled  = (float*)alloc(128 * 64 * 4);
    // fast-path extras (checked against ws_size)
    int*    csr_src = (int*)   alloc((size_t)E * 4);
    float4* csr_ea  = (float4*)alloc((size_t)E * 16 * 4);
    bool pre = ((size_t)(w - (char*)d_ws) <= ws_size);

    // one memset over deg..cursor (adjacent)
    hipMemsetAsync(deg, 0, (size_t)((char*)cursor - (char*)deg) + (size_t)N * 4, stream);

    // CSR build
    count_k<<<(E + 255) / 256, 256, 0, stream>>>(dst, E, deg);
    int nChunks = (N + 1023) / 1024;
    scan_chunk<<<nChunks, 1024, 0, stream>>>(deg, row_start, chunkSums, N);
    scan_sums<<<1, 128, 0, stream>>>(chunkSums, nChunks);
    scan_add<<<(N + 255) / 256, 256, 0, stream>>>(row_start, chunkSums, N, E);
    fill_k<<<(E + 255) / 256, 256, 0, stream>>>(dst, E, row_start, cursor, csr);
    // determinism: fix within-row order (atomic fill order is race-dependent)
    sort_rows_k<<<(N + 255) / 256, 256, 0, stream>>>(row_start, csr, N);

    // one-time edge-data permutation into CSR order
    if (pre) {
        gather_edges<<<((size_t)E * 4 + 255) / 256, 256, 0, stream>>>(
            csr, src, (const float4*)eattr, csr_src, csr_ea, E);
    }

    // 3 transformer layers
    const float* Hin = x;
    for (int l = 0; l < 3; ++l) {
        gemm_qkvs<<<2048, 128, 0, stream>>>(Hin,
            Wq + l * 4096, bq + l * 64, Wk + l * 4096, bk + l * 64,
            Wv + l * 4096, bv + l * 64, Wskip + l * 4096, bskip + l * 64,
            Q, KVh, S, N);
        if (pre) {
            attn_pre<<<4096, 256, 0, stream>>>(Q, (const unsigned int*)KVh, S,
                row_start, csr_src, (const float*)csr_ea,
                We + l * 1024, be + l * 64, H, N, (l < 2) ? 1 : 0);
        } else {
            attn_k<<<4096, 256, 0, stream>>>(Q, (const unsigned int*)KVh, S,
                row_start, csr, src, eattr,
                We + l * 1024, be + l * 64, H, N, (l < 2) ? 1 : 0);
        }
        Hin = H;
    }

    // deterministic pool + head
    pool_mean_k<<<128, 256, 0, stream>>>(Hin, batch, pooled, N);
    mlp_k<<<128, 64, 0, stream>>>(pooled, lin1_w, lin1_b, lin2_w, lin2_b,
                                  (float*)d_out);
}

// Round 14
// 964.663 us; speedup vs baseline: 1.0152x; 1.0136x over previous
//
#include <hip/hip_runtime.h>
#include <hip/hip_bf16.h>

#define NODES_C 64
#define HEADS 4
#define HEAD_D 16

// f32 -> bf16 with round-to-nearest-even (deterministic, branch-free)
__device__ __forceinline__ unsigned short f32_to_bf16(float f) {
    unsigned int x = __float_as_uint(f);
    unsigned int r = x + 0x7fffu + ((x >> 16) & 1u);
    return (unsigned short)(r >> 16);
}
// bf16 (raw ushort) -> f32
#define BF16_DEC(h) __uint_as_float(((unsigned int)(h)) << 16)

// ---------------------------------------------------------------------------
// CSR build
// ---------------------------------------------------------------------------
__global__ void count_k(const int* __restrict__ dst, int E, int* __restrict__ deg) {
    int e = blockIdx.x * blockDim.x + threadIdx.x;
    if (e < E) atomicAdd(&deg[dst[e]], 1);
}

__global__ __launch_bounds__(1024) void scan_chunk(const int* __restrict__ deg,
                                                   int* __restrict__ excl,
                                                   int* __restrict__ chunkSums, int N) {
    __shared__ int buf[1024];
    int i = blockIdx.x * 1024 + threadIdx.x;
    int v = (i < N) ? deg[i] : 0;
    buf[threadIdx.x] = v;
    __syncthreads();
    for (int off = 1; off < 1024; off <<= 1) {
        int t = (threadIdx.x >= off) ? buf[threadIdx.x - off] : 0;
        __syncthreads();
        buf[threadIdx.x] += t;
        __syncthreads();
    }
    if (i < N) excl[i] = buf[threadIdx.x] - v;   // exclusive within chunk
    if (threadIdx.x == 1023) chunkSums[blockIdx.x] = buf[1023];
}

__global__ __launch_bounds__(128) void scan_sums(int* __restrict__ chunkSums, int nChunks) {
    __shared__ int buf[128];
    int v = (threadIdx.x < nChunks) ? chunkSums[threadIdx.x] : 0;
    buf[threadIdx.x] = v;
    __syncthreads();
    for (int off = 1; off < 128; off <<= 1) {
        int t = (threadIdx.x >= off) ? buf[threadIdx.x - off] : 0;
        __syncthreads();
        buf[threadIdx.x] += t;
        __syncthreads();
    }
    if (threadIdx.x < nChunks) chunkSums[threadIdx.x] = buf[threadIdx.x] - v;  // exclusive
}

__global__ void scan_add(int* __restrict__ excl, const int* __restrict__ chunkSums,
                         int N, int E) {
    int i = blockIdx.x * blockDim.x + threadIdx.x;
    if (i < N) excl[i] += chunkSums[i >> 10];
    if (i == 0) excl[N] = E;
}

__global__ void fill_k(const int* __restrict__ dst, int E,
                       const int* __restrict__ row_start, int* __restrict__ cursor,
                       int* __restrict__ csr) {
    int e = blockIdx.x * blockDim.x + threadIdx.x;
    if (e < E) {
        int d = dst[e];
        int pos = atomicAdd(&cursor[d], 1);
        csr[row_start[d] + pos] = e;
    }
}

// ---------------------------------------------------------------------------
// DETERMINISM (verified R9): sort each CSR row by edge id so the atomic
// fill order doesn't leak into f32 summation order. One thread per row.
// ---------------------------------------------------------------------------
__global__ void sort_rows_k(const int* __restrict__ row_start, int* __restrict__ csr,
                            int N) {
    int i = blockIdx.x * blockDim.x + threadIdx.x;
    if (i >= N) return;
    int beg = row_start[i], end = row_start[i + 1];
    for (int p = beg + 1; p < end; ++p) {
        int key = csr[p];
        int j = p - 1;
        while (j >= beg && csr[j] > key) { csr[j + 1] = csr[j]; --j; }
        csr[j + 1] = key;
    }
}

// ---------------------------------------------------------------------------
// One-time edge-data permutation into CSR order, bf16 OUTPUT (R14):
// halves gather_edges write traffic (77->38 MB) and each attn layer's
// edge-attr read traffic. Equivalent to rounding input edge_attr to bf16.
// ---------------------------------------------------------------------------
__global__ void gather_edges(const int* __restrict__ csr, const int* __restrict__ srcA,
                             const float4* __restrict__ ea4,
                             int* __restrict__ csr_src,
                             unsigned short* __restrict__ csr_eah, int E) {
    int t = blockIdx.x * blockDim.x + threadIdx.x;
    int p = t >> 2, q = t & 3;
    if (p < E) {
        int e = csr[p];
        if (q == 0) csr_src[p] = srcA[e];
        float4 v = ea4[(size_t)e * 4 + q];
        ushort4 h;
        h.x = f32_to_bf16(v.x);  h.y = f32_to_bf16(v.y);
        h.z = f32_to_bf16(v.z);  h.w = f32_to_bf16(v.w);
        *(ushort4*)(csr_eah + (size_t)p * 16 + q * 4) = h;
    }
}

// ---------------------------------------------------------------------------
// Fused node projections, 2-column register tile (R13).
// K/V stored as BF16 PAIRS: KVh[n*128+2c]={K}, [..+1]={V} (verified R11).
// ---------------------------------------------------------------------------
#define GB 16
__global__ __launch_bounds__(128) void gemm_qkvs(
    const float* __restrict__ Hin,
    const float* __restrict__ Wq, const float* __restrict__ bq,
    const float* __restrict__ Wk, const float* __restrict__ bk,
    const float* __restrict__ Wv, const float* __restrict__ bv,
    const float* __restrict__ Ws, const float* __restrict__ bs,
    float* __restrict__ Q, unsigned short* __restrict__ KVh,
    float* __restrict__ Ssk, int N)
{
    int g = threadIdx.x >> 6;          // 0: Q+K, 1: V+S
    int c = threadIdx.x & 63;
    const float* W1 = (g == 0) ? Wq : Wv;
    const float* b1 = (g == 0) ? bq : bv;
    const float* W2 = (g == 0) ? Wk : Ws;
    const float* b2 = (g == 0) ? bk : bs;

    float w1[64], w2[64];
#pragma unroll
    for (int t = 0; t < 64; ++t) {
        w1[t] = W1[t * 64 + c];
        w2[t] = W2[t * 64 + c];
    }
    float bias1 = b1[c], bias2 = b2[c];

    __shared__ __align__(16) float hrow[GB][64];

    for (int base = blockIdx.x * GB; base < N; base += gridDim.x * GB) {
        int nn = min(GB, N - base);
        __syncthreads();
        for (int idx = threadIdx.x; idx < nn * 64; idx += 128)
            hrow[idx >> 6][idx & 63] = Hin[base * 64 + idx];
        __syncthreads();
        for (int r = 0; r < nn; ++r) {
            const float4* h4 = (const float4*)hrow[r];
            float acc1 = bias1, acc2 = bias2;
#pragma unroll
            for (int t4 = 0; t4 < 16; ++t4) {
                float4 hv = h4[t4];
                acc1 += hv.x * w1[4 * t4 + 0];
                acc1 += hv.y * w1[4 * t4 + 1];
                acc1 += hv.z * w1[4 * t4 + 2];
                acc1 += hv.w * w1[4 * t4 + 3];
                acc2 += hv.x * w2[4 * t4 + 0];
                acc2 += hv.y * w2[4 * t4 + 1];
                acc2 += hv.z * w2[4 * t4 + 2];
                acc2 += hv.w * w2[4 * t4 + 3];
            }
            size_t row = (size_t)(base + r);
            if (g == 0) {                                  // wave-uniform
                Q[row * 64 + c] = acc1;                    // Q  (f32)
                KVh[row * 128 + 2 * c] = f32_to_bf16(acc2);// K  (bf16)
            } else {
                KVh[row * 128 + 2 * c + 1] = f32_to_bf16(acc1); // V (bf16)
                Ssk[row * 64 + c] = acc2;                  // S  (f32)
            }
        }
    }
}

// ---------------------------------------------------------------------------
// Edge-softmax attention, bf16 KV + bf16 edge-attr + pipelined prefetch.
// Structure at its measured floor per R10/R11/R12; this round only the
// edge-attr loads shrink from dword to ushort.
// ---------------------------------------------------------------------------
#define KV_DECODE(u, kf, vf)                                \
    kf = __uint_as_float((u) << 16);                        \
    vf = __uint_as_float((u) & 0xffff0000u);

__global__ __launch_bounds__(256) void attn_pre(
    const float* __restrict__ Q, const unsigned int* __restrict__ KVu,
    const float* __restrict__ Ssk,
    const int* __restrict__ row_start, const int* __restrict__ csr_src,
    const unsigned short* __restrict__ csr_eah,   // [E][16] bf16, CSR order
    const float* __restrict__ We, const float* __restrict__ be,
    float* __restrict__ Hout, int N, int doRelu)
{
    __shared__ float weS[16 * 68];          // padded rows
    for (int idx = threadIdx.x; idx < 1024; idx += 256)
        weS[(idx >> 6) * 68 + (idx & 63)] = We[idx];
    __syncthreads();

    int lane = threadIdx.x & 63;
    int tl = lane & 15;                     // edge-attr dim owned by this lane
    int hb = lane & 48;                     // head base channel
    float wcol[16];
#pragma unroll
    for (int t = 0; t < 16; ++t) wcol[t] = weS[t * 68 + lane];
    float beL = be[lane];

    int gwave  = (blockIdx.x * blockDim.x + threadIdx.x) >> 6;
    int nwaves = (gridDim.x * blockDim.x) >> 6;

    const float4* wr4 = (const float4*)(weS + tl * 68 + hb);
    float4 wa = wr4[0], wb = wr4[1], wc4 = wr4[2], wd = wr4[3];

    for (int i = gwave; i < N; i += nwaves) {
        float q = Q[(size_t)i * 64 + lane];

        // ---- per-node prologue ----
        const float4* qh4 = (const float4*)(Q + (size_t)i * 64 + hb);
        float4 qa = qh4[0], qb4 = qh4[1], qc4 = qh4[2], qd = qh4[3];
        float G = qa.x * wa.x + qa.y * wa.y + qa.z * wa.z + qa.w * wa.w
                + qb4.x * wb.x + qb4.y * wb.y + qb4.z * wb.z + qb4.w * wb.w
                + qc4.x * wc4.x + qc4.y * wc4.y + qc4.z * wc4.z + qc4.w * wc4.w
                + qd.x * wd.x + qd.y * wd.y + qd.z * wd.z + qd.w * wd.w;
        float rb = q * beL;
#pragma unroll
        for (int off = 8; off >= 1; off >>= 1) rb += __shfl_xor(rb, off, 16);
        float qbase = rb * 0.25f;

        int beg = row_start[i], end = row_start[i + 1];
        float m = -INFINITY, s = 0.f, acc = 0.f, z = 0.f;

        int p = beg;
        // ---- 8-wide pipelined main loop ----
        if (p + 7 < end) {
            int j0 = csr_src[p],     j1 = csr_src[p + 1];
            int j2 = csr_src[p + 2], j3 = csr_src[p + 3];
            int j4 = csr_src[p + 4], j5 = csr_src[p + 5];
            int j6 = csr_src[p + 6], j7 = csr_src[p + 7];
            const unsigned short* eh = csr_eah + (size_t)p * 16 + tl;
            float a0 = BF16_DEC(eh[0]),  a1 = BF16_DEC(eh[16]);
            float a2 = BF16_DEC(eh[32]), a3 = BF16_DEC(eh[48]);
            float a4 = BF16_DEC(eh[64]), a5 = BF16_DEC(eh[80]);
            float a6 = BF16_DEC(eh[96]), a7 = BF16_DEC(eh[112]);

            do {
                unsigned int u0 = KVu[(size_t)j0 * 64 + lane];
                unsigned int u1 = KVu[(size_t)j1 * 64 + lane];
                unsigned int u2 = KVu[(size_t)j2 * 64 + lane];
                unsigned int u3 = KVu[(size_t)j3 * 64 + lane];
                unsigned int u4 = KVu[(size_t)j4 * 64 + lane];
                unsigned int u5 = KVu[(size_t)j5 * 64 + lane];
                unsigned int u6 = KVu[(size_t)j6 * 64 + lane];
                unsigned int u7 = KVu[(size_t)j7 * 64 + lane];

                int pn = p + 8;
                bool more = (pn + 7 < end);      // wave-uniform
                int jn0 = j0, jn1 = j1, jn2 = j2, jn3 = j3;
                int jn4 = j4, jn5 = j5, jn6 = j6, jn7 = j7;
                float an0 = a0, an1 = a1, an2 = a2, an3 = a3;
                float an4 = a4, an5 = a5, an6 = a6, an7 = a7;
                if (more) {
                    jn0 = csr_src[pn];     jn1 = csr_src[pn + 1];
                    jn2 = csr_src[pn + 2]; jn3 = csr_src[pn + 3];
                    jn4 = csr_src[pn + 4]; jn5 = csr_src[pn + 5];
                    jn6 = csr_src[pn + 6]; jn7 = csr_src[pn + 7];
                    const unsigned short* ehn = csr_eah + (size_t)pn * 16 + tl;
                    an0 = BF16_DEC(ehn[0]);  an1 = BF16_DEC(ehn[16]);
                    an2 = BF16_DEC(ehn[32]); an3 = BF16_DEC(ehn[48]);
                    an4 = BF16_DEC(ehn[64]); an5 = BF16_DEC(ehn[80]);
                    an6 = BF16_DEC(ehn[96]); an7 = BF16_DEC(ehn[112]);
                }

                float k0, v0, k1, v1, k2, v2, k3, v3, k4, v4, k5, v5, k6, v6, k7, v7;
                KV_DECODE(u0, k0, v0)  KV_DECODE(u1, k1, v1)
                KV_DECODE(u2, k2, v2)  KV_DECODE(u3, k3, v3)
                KV_DECODE(u4, k4, v4)  KV_DECODE(u5, k5, v5)
                KV_DECODE(u6, k6, v6)  KV_DECODE(u7, k7, v7)

                float l0 = q * k0 + a0 * G;
                float l1 = q * k1 + a1 * G;
                float l2 = q * k2 + a2 * G;
                float l3 = q * k3 + a3 * G;
                float l4 = q * k4 + a4 * G;
                float l5 = q * k5 + a5 * G;
                float l6 = q * k6 + a6 * G;
                float l7 = q * k7 + a7 * G;
#pragma unroll
                for (int off = 8; off >= 1; off >>= 1) {
                    l0 += __shfl_xor(l0, off, 16);
                    l1 += __shfl_xor(l1, off, 16);
                    l2 += __shfl_xor(l2, off, 16);
                    l3 += __shfl_xor(l3, off, 16);
                    l4 += __shfl_xor(l4, off, 16);
                    l5 += __shfl_xor(l5, off, 16);
                    l6 += __shfl_xor(l6, off, 16);
                    l7 += __shfl_xor(l7, off, 16);
                }
                l0 = l0 * 0.25f + qbase;  l1 = l1 * 0.25f + qbase;
                l2 = l2 * 0.25f + qbase;  l3 = l3 * 0.25f + qbase;
                l4 = l4 * 0.25f + qbase;  l5 = l5 * 0.25f + qbase;
                l6 = l6 * 0.25f + qbase;  l7 = l7 * 0.25f + qbase;

                float nm = fmaxf(fmaxf(fmaxf(l0, l1), fmaxf(l2, l3)),
                                 fmaxf(fmaxf(l4, l5), fmaxf(l6, l7)));
                nm = fmaxf(nm, m);
                float sc = __expf(m - nm);
                float w0 = __expf(l0 - nm), w1 = __expf(l1 - nm);
                float w2 = __expf(l2 - nm), w3 = __expf(l3 - nm);
                float w4 = __expf(l4 - nm), w5 = __expf(l5 - nm);
                float w6 = __expf(l6 - nm), w7 = __expf(l7 - nm);
                s   = s * sc + ((w0 + w1) + (w2 + w3)) + ((w4 + w5) + (w6 + w7));
                acc = acc * sc + ((w0 * v0 + w1 * v1) + (w2 * v2 + w3 * v3))
                               + ((w4 * v4 + w5 * v5) + (w6 * v6 + w7 * v7));
                z   = z * sc + ((w0 * a0 + w1 * a1) + (w2 * a2 + w3 * a3))
                             + ((w4 * a4 + w5 * a5) + (w6 * a6 + w7 * a7));
                m = nm;

                j0 = jn0; j1 = jn1; j2 = jn2; j3 = jn3;
                j4 = jn4; j5 = jn5; j6 = jn6; j7 = jn7;
                a0 = an0; a1 = an1; a2 = an2; a3 = an3;
                a4 = an4; a5 = an5; a6 = an6; a7 = an7;
                p = pn;
            } while (p + 7 < end);
        }
        // ---- 4-wide tail ----
        for (; p + 3 < end; p += 4) {
            int j0 = csr_src[p],     j1 = csr_src[p + 1];
            int j2 = csr_src[p + 2], j3 = csr_src[p + 3];
            unsigned int u0 = KVu[(size_t)j0 * 64 + lane];
            unsigned int u1 = KVu[(size_t)j1 * 64 + lane];
            unsigned int u2 = KVu[(size_t)j2 * 64 + lane];
            unsigned int u3 = KVu[(size_t)j3 * 64 + lane];
            const unsigned short* eh = csr_eah + (size_t)p * 16 + tl;
            float a0 = BF16_DEC(eh[0]),  a1 = BF16_DEC(eh[16]);
            float a2 = BF16_DEC(eh[32]), a3 = BF16_DEC(eh[48]);

            float k0, v0, k1, v1, k2, v2, k3, v3;
            KV_DECODE(u0, k0, v0)  KV_DECODE(u1, k1, v1)
            KV_DECODE(u2, k2, v2)  KV_DECODE(u3, k3, v3)

            float l0 = q * k0 + a0 * G;
            float l1 = q * k1 + a1 * G;
            float l2 = q * k2 + a2 * G;
            float l3 = q * k3 + a3 * G;
#pragma unroll
            for (int off = 8; off >= 1; off >>= 1) {
                l0 += __shfl_xor(l0, off, 16);
                l1 += __shfl_xor(l1, off, 16);
                l2 += __shfl_xor(l2, off, 16);
                l3 += __shfl_xor(l3, off, 16);
            }
            l0 = l0 * 0.25f + qbase;  l1 = l1 * 0.25f + qbase;
            l2 = l2 * 0.25f + qbase;  l3 = l3 * 0.25f + qbase;

            float nm = fmaxf(fmaxf(fmaxf(l0, l1), fmaxf(l2, l3)), m);
            float sc = __expf(m - nm);
            float w0 = __expf(l0 - nm), w1 = __expf(l1 - nm);
            float w2 = __expf(l2 - nm), w3 = __expf(l3 - nm);
            s   = s * sc + w0 + w1 + w2 + w3;
            acc = acc * sc + w0 * v0 + w1 * v1 + w2 * v2 + w3 * v3;
            z   = z * sc + w0 * a0 + w1 * a1 + w2 * a2 + w3 * a3;
            m = nm;
        }
        // ---- scalar tail ----
        for (; p < end; ++p) {
            int j = csr_src[p];
            unsigned int u = KVu[(size_t)j * 64 + lane];
            float a = BF16_DEC(csr_eah[(size_t)p * 16 + tl]);
            float kf, vf;
            KV_DECODE(u, kf, vf)
            float l = q * kf + a * G;
#pragma unroll
            for (int off = 8; off >= 1; off >>= 1) l += __shfl_xor(l, off, 16);
            l = l * 0.25f + qbase;
            float nm = fmaxf(m, l);
            float sc = __expf(m - nm);
            float w  = __expf(l - nm);
            s   = s * sc + w;
            acc = acc * sc + w * vf;
            z   = z * sc + w * a;
            m = nm;
        }

        // ---- epilogue: fold edge-projection back in ----
        float o;
        if (s > 0.f) {
            float t = acc;
#pragma unroll
            for (int u = 0; u < 16; ++u) t += wcol[u] * __shfl(z, u, 16);
            o = t / s + beL + Ssk[(size_t)i * 64 + lane];
        } else {
            o = Ssk[(size_t)i * 64 + lane];
        }
        if (doRelu) o = fmaxf(o, 0.f);
        Hout[(size_t)i * 64 + lane] = o;
    }
}

// ---------------------------------------------------------------------------
// Fallback attention (direct algorithm) — only if ws can't hold csr_eah.
// ---------------------------------------------------------------------------
__global__ __launch_bounds__(256) void attn_k(
    const float* __restrict__ Q, const unsigned int* __restrict__ KVu,
    const float* __restrict__ Ssk,
    const int* __restrict__ row_start, const int* __restrict__ csr,
    const int* __restrict__ srcA, const float* __restrict__ edge_attr,
    const float* __restrict__ We, const float* __restrict__ be,
    float* __restrict__ Hout, int N, int doRelu)
{
    int lane = threadIdx.x & 63;
    float wcol[16];
#pragma unroll
    for (int t = 0; t < 16; ++t) wcol[t] = We[t * 64 + lane];
    float beL = be[lane];

    int gwave  = (blockIdx.x * blockDim.x + threadIdx.x) >> 6;
    int nwaves = (gridDim.x * blockDim.x) >> 6;

    for (int i = gwave; i < N; i += nwaves) {
        float q = Q[(size_t)i * 64 + lane];
        int beg = row_start[i], end = row_start[i + 1];
        float m = -INFINITY, s = 0.f, acc = 0.f;
        for (int p = beg; p < end; ++p) {
            int e = csr[p];
            int j = srcA[e];
            const float4* ap = (const float4*)(edge_attr + (size_t)e * 16);
            float4 a0 = ap[0], a1 = ap[1], a2 = ap[2], a3 = ap[3];
            unsigned int u = KVu[(size_t)j * 64 + lane];
            float kf, vf;
            KV_DECODE(u, kf, vf)
            float ea = beL;
            ea += a0.x * wcol[0]  + a0.y * wcol[1]  + a0.z * wcol[2]  + a0.w * wcol[3];
            ea += a1.x * wcol[4]  + a1.y * wcol[5]  + a1.z * wcol[6]  + a1.w * wcol[7];
            ea += a2.x * wcol[8]  + a2.y * wcol[9]  + a2.z * wcol[10] + a2.w * wcol[11];
            ea += a3.x * wcol[12] + a3.y * wcol[13] + a3.z * wcol[14] + a3.w * wcol[15];
            float kv = kf + ea, vv = vf + ea;
            float part = q * kv;
#pragma unroll
            for (int off = 8; off >= 1; off >>= 1) part += __shfl_xor(part, off, 16);
            float logit = part * 0.25f;
            float nm = fmaxf(m, logit);
            float sc = __expf(m - nm);
            float w  = __expf(logit - nm);
            s = s * sc + w;  acc = acc * sc + w * vv;  m = nm;
        }
        float agg = (s > 0.f) ? acc / s : 0.f;
        float o = agg + Ssk[(size_t)i * 64 + lane];
        if (doRelu) o = fmaxf(o, 0.f);
        Hout[(size_t)i * 64 + lane] = o;
    }
}

// ---------------------------------------------------------------------------
// Deterministic global mean pool (verified R9): one block per graph,
// binary-searched boundaries, fixed-order LDS combine, no atomics.
// ---------------------------------------------------------------------------
__device__ __forceinline__ int lbound(const int* __restrict__ a, int n, int key) {
    int lo = 0, hi = n;
    while (lo < hi) { int mid = (lo + hi) >> 1; if (a[mid] < key) lo = mid + 1; else hi = mid; }
    return lo;
}

__global__ __launch_bounds__(256) void pool_mean_k(
    const float* __restrict__ H, const int* __restrict__ batch,
    float* __restrict__ pooled, int N)
{
    int g = blockIdx.x;
    int lo = lbound(batch, N, g);
    int hi = lbound(batch, N, g + 1);
    int lane = threadIdx.x & 63;
    int w = threadIdx.x >> 6;

    float acc = 0.f;
    for (int i = lo + w; i < hi; i += 4)
        acc += H[(size_t)i * 64 + lane];

    __shared__ float part[4][64];
    part[w][lane] = acc;
    __syncthreads();
    if (w == 0) {
        float s = ((part[0][lane] + part[1][lane]) + part[2][lane]) + part[3][lane];
        float cnt = (float)(hi - lo);
        pooled[g * 64 + lane] = s / fmaxf(cnt, 1.0f);
    }
}

__global__ __launch_bounds__(64) void mlp_k(
    const float* __restrict__ pooled,      // means
    const float* __restrict__ lin1_w, const float* __restrict__ lin1_b,
    const float* __restrict__ lin2_w, const float* __restrict__ lin2_b,
    float* __restrict__ out)
{
    int g = blockIdx.x;
    int c = threadIdx.x;
    float acc = lin1_b[c];
#pragma unroll
    for (int t = 0; t < 64; ++t) acc += pooled[g * 64 + t] * lin1_w[t * 64 + c];
    float r = fmaxf(acc, 0.f) * lin2_w[c];
#pragma unroll
    for (int off = 32; off >= 1; off >>= 1) r += __shfl_xor(r, off, 64);
    if (c == 0) out[g] = r + lin2_b[0];
}

// ---------------------------------------------------------------------------
extern "C" void kernel_launch(void* const* d_in, const int* in_sizes, int n_in,
                              void* d_out, int out_size, void* d_ws, size_t ws_size,
                              hipStream_t stream) {
    const float* x        = (const float*)d_in[0];
    const int*   eidx     = (const int*)  d_in[1];
    const float* eattr    = (const float*)d_in[2];
    const int*   batch    = (const int*)  d_in[3];
    const float* Wq       = (const float*)d_in[4];
    const float* bq       = (const float*)d_in[5];
    const float* Wk       = (const float*)d_in[6];
    const float* bk       = (const float*)d_in[7];
    const float* Wv       = (const float*)d_in[8];
    const float* bv       = (const float*)d_in[9];
    const float* We       = (const float*)d_in[10];
    const float* be       = (const float*)d_in[11];
    const float* Wskip    = (const float*)d_in[12];
    const float* bskip    = (const float*)d_in[13];
    const float* lin1_w   = (const float*)d_in[14];
    const float* lin1_b   = (const float*)d_in[15];
    const float* lin2_w   = (const float*)d_in[16];
    const float* lin2_b   = (const float*)d_in[17];

    int N = in_sizes[0] / 64;
    int E = in_sizes[1] / 2;
    const int* src = eidx;
    const int* dst = eidx + E;

    // workspace layout
    char* w = (char*)d_ws;
    auto alloc = [&](size_t bytes) {
        char* p = w;
        w += (bytes + 255) & ~(size_t)255;
        return p;
    };
    float* Q   = (float*)alloc((size_t)N * 64 * 4);
    unsigned short* KVh = (unsigned short*)alloc((size_t)N * 128 * 2);  // bf16 {K,V} pairs
    float* S   = (float*)alloc((size_t)N * 64 * 4);
    float* H   = (float*)alloc((size_t)N * 64 * 4);
    // deg and cursor adjacent -> single memset covers both
    int* deg       = (int*)alloc((size_t)N * 4);
    int* cursor    = (int*)alloc((size_t)N * 4);
    int* row_start = (int*)alloc((size_t)(N + 1) * 4);
    int* csr       = (int*)alloc((size_t)E * 4);
    int* chunkSums = (int*)alloc(128 * 4);
    float* pooled  = (float*)alloc(128 * 64 * 4);
    // fast-path extras (checked against ws_size)
    int* csr_src              = (int*)alloc((size_t)E * 4);
    unsigned short* csr_eah   = (unsigned short*)alloc((size_t)E * 16 * 2);  // bf16
    bool pre = ((size_t)(w - (char*)d_ws) <= ws_size);

    // one memset over deg..cursor (adjacent)
    hipMemsetAsync(deg, 0, (size_t)((char*)cursor - (char*)deg) + (size_t)N * 4, stream);

    // CSR build
    count_k<<<(E + 255) / 256, 256, 0, stream>>>(dst, E, deg);
    int nChunks = (N + 1023) / 1024;
    scan_chunk<<<nChunks, 1024, 0, stream>>>(deg, row_start, chunkSums, N);
    scan_sums<<<1, 128, 0, stream>>>(chunkSums, nChunks);
    scan_add<<<(N + 255) / 256, 256, 0, stream>>>(row_start, chunkSums, N, E);
    fill_k<<<(E + 255) / 256, 256, 0, stream>>>(dst, E, row_start, cursor, csr);
    // determinism: fix within-row order (atomic fill order is race-dependent)
    sort_rows_k<<<(N + 255) / 256, 256, 0, stream>>>(row_start, csr, N);

    // one-time edge-data permutation into CSR order (bf16 output)
    if (pre) {
        gather_edges<<<((size_t)E * 4 + 255) / 256, 256, 0, stream>>>(
            csr, src, (const float4*)eattr, csr_src, csr_eah, E);
    }

    // 3 transformer layers
    const float* Hin = x;
    for (int l = 0; l < 3; ++l) {
        gemm_qkvs<<<2048, 128, 0, stream>>>(Hin,
            Wq + l * 4096, bq + l * 64, Wk + l * 4096, bk + l * 64,
            Wv + l * 4096, bv + l * 64, Wskip + l * 4096, bskip + l * 64,
            Q, KVh, S, N);
        if (pre) {
            attn_pre<<<4096, 256, 0, stream>>>(Q, (const unsigned int*)KVh, S,
                row_start, csr_src, csr_eah,
                We + l * 1024, be + l * 64, H, N, (l < 2) ? 1 : 0);
        } else {
            attn_k<<<4096, 256, 0, stream>>>(Q, (const unsigned int*)KVh, S,
                row_start, csr, src, eattr,
                We + l * 1024, be + l * 64, H, N, (l < 2) ? 1 : 0);
        }
        Hin = H;
    }

    // deterministic pool + head
    pool_mean_k<<<128, 256, 0, stream>>>(Hin, batch, pooled, N);
    mlp_k<<<128, 64, 0, stream>>>(pooled, lin1_w, lin1_b, lin2_w, lin2_b,
                                  (float*)d_out);
}